// Round 1
// baseline (487.393 us; speedup 1.0000x reference)
//
#include <hip/hip_runtime.h>
#include <hip/hip_bf16.h>
#include <stdint.h>

#define DM   1024
#define NH   16
#define DHD  64
#define BB   2
#define NQS  2048
#define NKVS 2048

typedef __attribute__((ext_vector_type(8))) short short8;
typedef __attribute__((ext_vector_type(4))) float f32x4;
typedef __attribute__((ext_vector_type(4))) unsigned short us4;

static __device__ __forceinline__ unsigned short f2bf(float f) {
  union { float f; unsigned u; } v; v.f = f;
  unsigned r = (v.u + 0x7fffu + ((v.u >> 16) & 1u)) >> 16;
  return (unsigned short)r;
}

#define MFMA(a, b, c) __builtin_amdgcn_mfma_f32_16x16x32_bf16((a), (b), (c), 0, 0, 0)

// ---------------------------------------------------------------------------
// Kernel 0: transpose weights fp32 [K][J] -> bf16 Wt [J][K]
// grid (16,16,4), block 256
__global__ __launch_bounds__(256) void wt_kernel(
    const float* __restrict__ Wq, const float* __restrict__ Wk,
    const float* __restrict__ Wv, const float* __restrict__ Wo,
    unsigned short* __restrict__ wt) {
  __shared__ unsigned short Ls[64][68];
  const int z = blockIdx.z;
  const float* W = (z == 0) ? Wq : (z == 1) ? Wk : (z == 2) ? Wv : Wo;
  unsigned short* out = wt + (size_t)z * 1024 * 1024;
  const int r0 = blockIdx.y * 64, c0 = blockIdx.x * 64;
  const int t = threadIdx.x;
#pragma unroll
  for (int i = 0; i < 4; i++) {
    int idx = t + 256 * i;
    int row = idx >> 4, c4 = (idx & 15) * 4;
    float4 v = *(const float4*)(W + (size_t)(r0 + row) * 1024 + c0 + c4);
    Ls[row][c4 + 0] = f2bf(v.x);
    Ls[row][c4 + 1] = f2bf(v.y);
    Ls[row][c4 + 2] = f2bf(v.z);
    Ls[row][c4 + 3] = f2bf(v.w);
  }
  __syncthreads();
#pragma unroll
  for (int i = 0; i < 4; i++) {
    int idx = t + 256 * i;
    int jj = idx >> 4, k4 = (idx & 15) * 4;
    us4 o;
    o[0] = Ls[k4 + 0][jj];
    o[1] = Ls[k4 + 1][jj];
    o[2] = Ls[k4 + 2][jj];
    o[3] = Ls[k4 + 3][jj];
    *(us4*)(out + (size_t)(c0 + jj) * 1024 + r0 + k4) = o;
  }
}

// ---------------------------------------------------------------------------
// Kernel 1: pack mask int32 -> bitmask (bit=1 means keep)
__global__ __launch_bounds__(256) void maskpack_kernel(
    const int* __restrict__ mask, unsigned long long* __restrict__ pk) {
  const long long total = (long long)BB * NQS * NKVS;
  const long long stride = (long long)gridDim.x * 256;
  for (long long i = (long long)blockIdx.x * 256 + threadIdx.x; i < total; i += stride) {
    int m = mask[i];
    unsigned long long b = __ballot(m != 0);
    if ((i & 63) == 0) pk[i >> 6] = b;
  }
}

// ---------------------------------------------------------------------------
// Kernel 2: fused QKV projection GEMM. z=0:Q(*0.125)->[B,H,N,d], z=1:K->[B,H,N,d],
// z=2:V->[B,H,d,N] (transposed). M=4096,N=1024,K=1024. 128x128 tile, BK=64.
__global__ __launch_bounds__(256) void proj_kernel(
    const float* __restrict__ Qin, const float* __restrict__ Kin, const float* __restrict__ Vin,
    const unsigned short* __restrict__ wt,
    const float* __restrict__ bq, const float* __restrict__ bk, const float* __restrict__ bv,
    unsigned short* __restrict__ q_ws, unsigned short* __restrict__ k_ws,
    unsigned short* __restrict__ v_ws) {
  __shared__ unsigned short As[128 * 72];
  __shared__ unsigned short Bs[128 * 72];
  const int z = blockIdx.z;
  const float* X = (z == 0) ? Qin : (z == 1) ? Kin : Vin;
  const float* bias = (z == 0) ? bq : (z == 1) ? bk : bv;
  const unsigned short* Wt = wt + (size_t)z * 1024 * 1024;
  const int m0 = blockIdx.y * 128, j0 = blockIdx.x * 128;
  const int t = threadIdx.x, wid = t >> 6, lane = t & 63, lr = lane & 15, lg = lane >> 4;
  const int wm = wid >> 1, wn = wid & 1;

  f32x4 acc[4][4] = {};
  for (int kt = 0; kt < 16; kt++) {
    const int k0 = kt * 64;
#pragma unroll
    for (int i = 0; i < 8; i++) {  // stage A: fp32 -> bf16
      int idx = t + 256 * i;
      int row = idx >> 4, c4 = (idx & 15) * 4;
      float4 v = *(const float4*)(X + (size_t)(m0 + row) * 1024 + k0 + c4);
      us4 o;
      o[0] = f2bf(v.x); o[1] = f2bf(v.y); o[2] = f2bf(v.z); o[3] = f2bf(v.w);
      *(us4*)(&As[row * 72 + c4]) = o;
    }
#pragma unroll
    for (int i = 0; i < 4; i++) {  // stage B (already bf16, [j][k])
      int idx = t + 256 * i;
      int j = idx >> 3, c8 = (idx & 7) * 8;
      short8 v = *(const short8*)(Wt + (size_t)(j0 + j) * 1024 + k0 + c8);
      *(short8*)(&Bs[j * 72 + c8]) = v;
    }
    __syncthreads();
    short8 a[2][4], b[2][4];
#pragma unroll
    for (int ks = 0; ks < 2; ks++)
#pragma unroll
      for (int mf = 0; mf < 4; mf++)
        a[ks][mf] = *(const short8*)(&As[(wm * 64 + mf * 16 + lr) * 72 + ks * 32 + lg * 8]);
#pragma unroll
    for (int ks = 0; ks < 2; ks++)
#pragma unroll
      for (int nf = 0; nf < 4; nf++)
        b[ks][nf] = *(const short8*)(&Bs[(wn * 64 + nf * 16 + lr) * 72 + ks * 32 + lg * 8]);
#pragma unroll
    for (int ks = 0; ks < 2; ks++)
#pragma unroll
      for (int mf = 0; mf < 4; mf++)
#pragma unroll
        for (int nf = 0; nf < 4; nf++)
          acc[mf][nf] = MFMA(a[ks][mf], b[ks][nf], acc[mf][nf]);
    __syncthreads();
  }
  // epilogue
#pragma unroll
  for (int nf = 0; nf < 4; nf++) {
    const int j = j0 + wn * 64 + nf * 16 + lr;
    const float bj = bias[j];
    const int h = j >> 6, dd = j & 63;
#pragma unroll
    for (int mf = 0; mf < 4; mf++) {
      const int mb = m0 + wm * 64 + mf * 16 + lg * 4;
      const int b_ = mb >> 11, nb = mb & 2047;
      if (z == 2) {
        us4 o;
#pragma unroll
        for (int r = 0; r < 4; r++) o[r] = f2bf(acc[mf][nf][r] + bj);
        *(us4*)(v_ws + ((size_t)(b_ * NH + h) * DHD + dd) * NKVS + nb) = o;
      } else {
        unsigned short* dst = (z == 0) ? q_ws : k_ws;
        const float sc = (z == 0) ? 0.125f : 1.0f;
#pragma unroll
        for (int r = 0; r < 4; r++) {
          float val = (acc[mf][nf][r] + bj) * sc;
          dst[((size_t)(b_ * NH + h) * NQS + nb + r) * DHD + dd] = f2bf(val);
        }
      }
    }
  }
}

// ---------------------------------------------------------------------------
// Kernel 3: flash attention. grid (32,16,2), block 256 (4 waves x 16 q-rows).
__global__ __launch_bounds__(256) void attn_kernel(
    const unsigned short* __restrict__ q_ws, const unsigned short* __restrict__ k_ws,
    const unsigned short* __restrict__ v_ws, const unsigned long long* __restrict__ pk,
    unsigned short* __restrict__ o_ws) {
  __shared__ unsigned short Pl[4][16 * 72];
  const int qt = blockIdx.x, h = blockIdx.y, b = blockIdx.z;
  const int bh = b * NH + h;
  const int t = threadIdx.x, wid = t >> 6, lane = t & 63, lr = lane & 15, lg = lane >> 4;
  const int qbase = qt * 64 + wid * 16;

  const size_t qoff = ((size_t)bh * NQS + qbase + lr) * DHD + lg * 8;
  const short8 qa0 = *(const short8*)(q_ws + qoff);
  const short8 qa1 = *(const short8*)(q_ws + qoff + 32);

  f32x4 O[4] = {};
  float mrow[4], lrow[4];
#pragma unroll
  for (int r = 0; r < 4; r++) { mrow[r] = -1e30f; lrow[r] = 0.f; }
  unsigned short* P = &Pl[wid][0];

  for (int kt = 0; kt < 32; kt++) {
    const int kv0 = kt * 64;
    f32x4 s[4];
#pragma unroll
    for (int cf = 0; cf < 4; cf++) {  // S = (q/8) . K^T
      const size_t ko = ((size_t)bh * NKVS + kv0 + cf * 16 + lr) * DHD + lg * 8;
      short8 kb0 = *(const short8*)(k_ws + ko);
      short8 kb1 = *(const short8*)(k_ws + ko + 32);
      f32x4 zz = {};
      s[cf] = MFMA(qa0, kb0, zz);
      s[cf] = MFMA(qa1, kb1, s[cf]);
    }
    unsigned long long mw[4];
#pragma unroll
    for (int r = 0; r < 4; r++)
      mw[r] = pk[((size_t)b * NQS + qbase + lg * 4 + r) * 32 + kt];
#pragma unroll
    for (int r = 0; r < 4; r++) {
      float mx = -1e30f;
#pragma unroll
      for (int cf = 0; cf < 4; cf++) {
        bool bit = (mw[r] >> (cf * 16 + lr)) & 1ull;
        mx = fmaxf(mx, bit ? s[cf][r] : -1e30f);
      }
#pragma unroll
      for (int off = 1; off < 16; off <<= 1) mx = fmaxf(mx, __shfl_xor(mx, off));
      const float mn = fmaxf(mrow[r], mx);
      const float sc = __expf(mrow[r] - mn);
      mrow[r] = mn;
      float rs = 0.f, pv[4];
#pragma unroll
      for (int cf = 0; cf < 4; cf++) {
        bool bit = (mw[r] >> (cf * 16 + lr)) & 1ull;
        float p = bit ? __expf(s[cf][r] - mn) : 0.f;
        pv[cf] = p;
        rs += p;
      }
#pragma unroll
      for (int off = 1; off < 16; off <<= 1) rs += __shfl_xor(rs, off);
      lrow[r] = lrow[r] * sc + rs;
#pragma unroll
      for (int df = 0; df < 4; df++) O[df][r] *= sc;
#pragma unroll
      for (int cf = 0; cf < 4; cf++)
        P[(lg * 4 + r) * 72 + cf * 16 + lr] = f2bf(pv[cf]);
    }
    const short8 pa0 = *(const short8*)(&P[lr * 72 + lg * 8]);
    const short8 pa1 = *(const short8*)(&P[lr * 72 + 32 + lg * 8]);
#pragma unroll
    for (int df = 0; df < 4; df++) {  // O += P . V
      const size_t vo = ((size_t)bh * DHD + df * 16 + lr) * NKVS + kv0 + lg * 8;
      short8 vb0 = *(const short8*)(v_ws + vo);
      short8 vb1 = *(const short8*)(v_ws + vo + 32);
      O[df] = MFMA(pa0, vb0, O[df]);
      O[df] = MFMA(pa1, vb1, O[df]);
    }
  }
#pragma unroll
  for (int r = 0; r < 4; r++) {
    const float rinv = (lrow[r] > 0.f) ? 1.f / lrow[r] : 0.f;
    const int n = qbase + lg * 4 + r;
#pragma unroll
    for (int df = 0; df < 4; df++)
      o_ws[((size_t)b * NQS + n) * DM + h * DHD + df * 16 + lr] = f2bf(O[df][r] * rinv);
  }
}

// ---------------------------------------------------------------------------
// Kernel 4: output projection: o_ws bf16 [4096][1024] @ Wo^T bf16 + b_o -> fp32
__global__ __launch_bounds__(256) void outproj_kernel(
    const unsigned short* __restrict__ Ain, const unsigned short* __restrict__ Wt,
    const float* __restrict__ bo, float* __restrict__ out) {
  __shared__ unsigned short As[128 * 72];
  __shared__ unsigned short Bs[128 * 72];
  const int m0 = blockIdx.y * 128, j0 = blockIdx.x * 128;
  const int t = threadIdx.x, wid = t >> 6, lane = t & 63, lr = lane & 15, lg = lane >> 4;
  const int wm = wid >> 1, wn = wid & 1;

  f32x4 acc[4][4] = {};
  for (int kt = 0; kt < 16; kt++) {
    const int k0 = kt * 64;
#pragma unroll
    for (int i = 0; i < 4; i++) {
      int idx = t + 256 * i;
      int row = idx >> 3, c8 = (idx & 7) * 8;
      *(short8*)(&As[row * 72 + c8]) =
          *(const short8*)(Ain + (size_t)(m0 + row) * 1024 + k0 + c8);
    }
#pragma unroll
    for (int i = 0; i < 4; i++) {
      int idx = t + 256 * i;
      int j = idx >> 3, c8 = (idx & 7) * 8;
      *(short8*)(&Bs[j * 72 + c8]) =
          *(const short8*)(Wt + (size_t)(j0 + j) * 1024 + k0 + c8);
    }
    __syncthreads();
    short8 a[2][4], b[2][4];
#pragma unroll
    for (int ks = 0; ks < 2; ks++)
#pragma unroll
      for (int mf = 0; mf < 4; mf++)
        a[ks][mf] = *(const short8*)(&As[(wm * 64 + mf * 16 + lr) * 72 + ks * 32 + lg * 8]);
#pragma unroll
    for (int ks = 0; ks < 2; ks++)
#pragma unroll
      for (int nf = 0; nf < 4; nf++)
        b[ks][nf] = *(const short8*)(&Bs[(wn * 64 + nf * 16 + lr) * 72 + ks * 32 + lg * 8]);
#pragma unroll
    for (int ks = 0; ks < 2; ks++)
#pragma unroll
      for (int mf = 0; mf < 4; mf++)
#pragma unroll
        for (int nf = 0; nf < 4; nf++)
          acc[mf][nf] = MFMA(a[ks][mf], b[ks][nf], acc[mf][nf]);
    __syncthreads();
  }
#pragma unroll
  for (int nf = 0; nf < 4; nf++) {
    const int j = j0 + wn * 64 + nf * 16 + lr;
    const float bj = bo[j];
#pragma unroll
    for (int mf = 0; mf < 4; mf++) {
      const int mb = m0 + wm * 64 + mf * 16 + lg * 4;
#pragma unroll
      for (int r = 0; r < 4; r++)
        out[(size_t)(mb + r) * 1024 + j] = acc[mf][nf][r] + bj;
    }
  }
}

// ---------------------------------------------------------------------------
extern "C" void kernel_launch(void* const* d_in, const int* in_sizes, int n_in,
                              void* d_out, int out_size, void* d_ws, size_t ws_size,
                              hipStream_t stream) {
  (void)in_sizes; (void)n_in; (void)out_size; (void)ws_size;
  const float* Q  = (const float*)d_in[0];
  const float* K  = (const float*)d_in[1];
  const float* V  = (const float*)d_in[2];
  const int* mask = (const int*)d_in[3];
  const float* Wq = (const float*)d_in[4];
  const float* bq = (const float*)d_in[5];
  const float* Wk = (const float*)d_in[6];
  const float* bk = (const float*)d_in[7];
  const float* Wv = (const float*)d_in[8];
  const float* bv = (const float*)d_in[9];
  const float* Wo = (const float*)d_in[10];
  const float* bo = (const float*)d_in[11];
  float* out = (float*)d_out;

  char* ws = (char*)d_ws;
  const size_t SZ_BHND = (size_t)BB * NH * NQS * DHD * 2;  // 8388608
  unsigned short* q_ws = (unsigned short*)(ws);
  unsigned short* k_ws = (unsigned short*)(ws + SZ_BHND);
  unsigned short* v_ws = (unsigned short*)(ws + 2 * SZ_BHND);
  unsigned short* o_ws = (unsigned short*)(ws + 3 * SZ_BHND);
  unsigned short* wt   = (unsigned short*)(ws + 4 * SZ_BHND);
  unsigned long long* pk = (unsigned long long*)(ws + 5 * SZ_BHND);

  hipLaunchKernelGGL(wt_kernel, dim3(16, 16, 4), dim3(256), 0, stream, Wq, Wk, Wv, Wo, wt);
  hipLaunchKernelGGL(maskpack_kernel, dim3(4096), dim3(256), 0, stream, mask, pk);
  hipLaunchKernelGGL(proj_kernel, dim3(8, 32, 3), dim3(256), 0, stream,
                     Q, K, V, wt, bq, bk, bv, q_ws, k_ws, v_ws);
  hipLaunchKernelGGL(attn_kernel, dim3(32, 16, 2), dim3(256), 0, stream,
                     q_ws, k_ws, v_ws, pk, o_ws);
  hipLaunchKernelGGL(outproj_kernel, dim3(8, 32), dim3(256), 0, stream,
                     o_ws, wt + (size_t)3 * 1024 * 1024, bo, out);
}

// Round 3
// 479.191 us; speedup vs baseline: 1.0171x; 1.0171x over previous
//
#include <hip/hip_runtime.h>
#include <hip/hip_bf16.h>
#include <stdint.h>

#define DM   1024
#define NH   16
#define DHD  64
#define BB   2
#define NQS  2048
#define NKVS 2048

typedef __attribute__((ext_vector_type(8))) short short8;
typedef __attribute__((ext_vector_type(4))) float f32x4;
typedef __attribute__((ext_vector_type(4))) unsigned short us4;

static __device__ __forceinline__ unsigned short f2bf(float f) {
  union { float f; unsigned u; } v; v.f = f;
  unsigned r = (v.u + 0x7fffu + ((v.u >> 16) & 1u)) >> 16;
  return (unsigned short)r;
}

#define MFMA(a, b, c) __builtin_amdgcn_mfma_f32_16x16x32_bf16((a), (b), (c), 0, 0, 0)

// ---------------------------------------------------------------------------
// Kernel 0: transpose weights fp32 [K][J] -> bf16 Wt [J][K]
__global__ __launch_bounds__(256) void wt_kernel(
    const float* __restrict__ Wq, const float* __restrict__ Wk,
    const float* __restrict__ Wv, const float* __restrict__ Wo,
    unsigned short* __restrict__ wt) {
  __shared__ unsigned short Ls[64][68];
  const int z = blockIdx.z;
  const float* W = (z == 0) ? Wq : (z == 1) ? Wk : (z == 2) ? Wv : Wo;
  unsigned short* out = wt + (size_t)z * 1024 * 1024;
  const int r0 = blockIdx.y * 64, c0 = blockIdx.x * 64;
  const int t = threadIdx.x;
#pragma unroll
  for (int i = 0; i < 4; i++) {
    int idx = t + 256 * i;
    int row = idx >> 4, c4 = (idx & 15) * 4;
    float4 v = *(const float4*)(W + (size_t)(r0 + row) * 1024 + c0 + c4);
    Ls[row][c4 + 0] = f2bf(v.x);
    Ls[row][c4 + 1] = f2bf(v.y);
    Ls[row][c4 + 2] = f2bf(v.z);
    Ls[row][c4 + 3] = f2bf(v.w);
  }
  __syncthreads();
#pragma unroll
  for (int i = 0; i < 4; i++) {
    int idx = t + 256 * i;
    int jj = idx >> 4, k4 = (idx & 15) * 4;
    us4 o;
    o[0] = Ls[k4 + 0][jj];
    o[1] = Ls[k4 + 1][jj];
    o[2] = Ls[k4 + 2][jj];
    o[3] = Ls[k4 + 3][jj];
    *(us4*)(out + (size_t)(c0 + jj) * 1024 + r0 + k4) = o;
  }
}

// ---------------------------------------------------------------------------
// Kernel 1: pack mask int32 -> bitmask (bit=1 means keep)
__global__ __launch_bounds__(256) void maskpack_kernel(
    const int* __restrict__ mask, unsigned long long* __restrict__ pk) {
  const long long total = (long long)BB * NQS * NKVS;
  const long long stride = (long long)gridDim.x * 256;
  for (long long i = (long long)blockIdx.x * 256 + threadIdx.x; i < total; i += stride) {
    int m = mask[i];
    unsigned long long b = __ballot(m != 0);
    if ((i & 63) == 0) pk[i >> 6] = b;
  }
}

// ---------------------------------------------------------------------------
// Kernel 2: fused QKV projection GEMM.
__global__ __launch_bounds__(256) void proj_kernel(
    const float* __restrict__ Qin, const float* __restrict__ Kin, const float* __restrict__ Vin,
    const unsigned short* __restrict__ wt,
    const float* __restrict__ bq, const float* __restrict__ bk, const float* __restrict__ bv,
    unsigned short* __restrict__ q_ws, unsigned short* __restrict__ k_ws,
    unsigned short* __restrict__ v_ws) {
  __shared__ unsigned short As[128 * 72];
  __shared__ unsigned short Bs[128 * 72];
  const int z = blockIdx.z;
  const float* X = (z == 0) ? Qin : (z == 1) ? Kin : Vin;
  const float* bias = (z == 0) ? bq : (z == 1) ? bk : bv;
  const unsigned short* Wt = wt + (size_t)z * 1024 * 1024;
  const int m0 = blockIdx.y * 128, j0 = blockIdx.x * 128;
  const int t = threadIdx.x, wid = t >> 6, lane = t & 63, lr = lane & 15, lg = lane >> 4;
  const int wm = wid >> 1, wn = wid & 1;

  f32x4 acc[4][4] = {};
  for (int kt = 0; kt < 16; kt++) {
    const int k0 = kt * 64;
#pragma unroll
    for (int i = 0; i < 8; i++) {
      int idx = t + 256 * i;
      int row = idx >> 4, c4 = (idx & 15) * 4;
      float4 v = *(const float4*)(X + (size_t)(m0 + row) * 1024 + k0 + c4);
      us4 o;
      o[0] = f2bf(v.x); o[1] = f2bf(v.y); o[2] = f2bf(v.z); o[3] = f2bf(v.w);
      *(us4*)(&As[row * 72 + c4]) = o;
    }
#pragma unroll
    for (int i = 0; i < 4; i++) {
      int idx = t + 256 * i;
      int j = idx >> 3, c8 = (idx & 7) * 8;
      short8 v = *(const short8*)(Wt + (size_t)(j0 + j) * 1024 + k0 + c8);
      *(short8*)(&Bs[j * 72 + c8]) = v;
    }
    __syncthreads();
    short8 a[2][4], b[2][4];
#pragma unroll
    for (int ks = 0; ks < 2; ks++)
#pragma unroll
      for (int mf = 0; mf < 4; mf++)
        a[ks][mf] = *(const short8*)(&As[(wm * 64 + mf * 16 + lr) * 72 + ks * 32 + lg * 8]);
#pragma unroll
    for (int ks = 0; ks < 2; ks++)
#pragma unroll
      for (int nf = 0; nf < 4; nf++)
        b[ks][nf] = *(const short8*)(&Bs[(wn * 64 + nf * 16 + lr) * 72 + ks * 32 + lg * 8]);
#pragma unroll
    for (int ks = 0; ks < 2; ks++)
#pragma unroll
      for (int mf = 0; mf < 4; mf++)
#pragma unroll
        for (int nf = 0; nf < 4; nf++)
          acc[mf][nf] = MFMA(a[ks][mf], b[ks][nf], acc[mf][nf]);
    __syncthreads();
  }
#pragma unroll
  for (int nf = 0; nf < 4; nf++) {
    const int j = j0 + wn * 64 + nf * 16 + lr;
    const float bj = bias[j];
    const int h = j >> 6, dd = j & 63;
#pragma unroll
    for (int mf = 0; mf < 4; mf++) {
      const int mb = m0 + wm * 64 + mf * 16 + lg * 4;
      const int b_ = mb >> 11, nb = mb & 2047;
      if (z == 2) {
        us4 o;
#pragma unroll
        for (int r = 0; r < 4; r++) o[r] = f2bf(acc[mf][nf][r] + bj);
        *(us4*)(v_ws + ((size_t)(b_ * NH + h) * DHD + dd) * NKVS + nb) = o;
      } else {
        unsigned short* dst = (z == 0) ? q_ws : k_ws;
        const float sc = (z == 0) ? 0.125f : 1.0f;
#pragma unroll
        for (int r = 0; r < 4; r++) {
          float val = (acc[mf][nf][r] + bj) * sc;
          dst[((size_t)(b_ * NH + h) * NQS + nb + r) * DHD + dd] = f2bf(val);
        }
      }
    }
  }
}

// ---------------------------------------------------------------------------
// Kernel 3: flash attention, swapped-operand form.
// Lane owns one q-row (q = lane&15): softmax reductions are 15 in-reg ops +
// 2 shfl_xor. P^T round-trips a wave-private XOR-swizzled 2KB LDS buffer.
// grid (32,16,2), block 256 (4 waves x 16 q).
__global__ __launch_bounds__(256) void attn_kernel(
    const unsigned short* __restrict__ q_ws, const unsigned short* __restrict__ k_ws,
    const unsigned short* __restrict__ v_ws, const unsigned long long* __restrict__ pk,
    unsigned short* __restrict__ o_ws) {
  __shared__ unsigned char Pl[4][2048];
  const int qt = blockIdx.x, h = blockIdx.y, b = blockIdx.z;
  const int bh = b * NH + h;
  const int t = threadIdx.x, wid = t >> 6, lane = t & 63, lr = lane & 15, lg = lane >> 4;
  const int q = qt * 64 + wid * 16 + lr;

  // Q as B-operand: lane holds Q[q=lr][d = lg*8..]
  const size_t qoff = ((size_t)bh * NQS + q) * DHD + lg * 8;
  const short8 qb0 = *(const short8*)(q_ws + qoff);
  const short8 qb1 = *(const short8*)(q_ws + qoff + 32);

  const unsigned long long* mp = pk + ((size_t)b * NQS + q) * 32;
  const unsigned short* kbase = k_ws + (size_t)bh * NQS * DHD;
  const unsigned short* vbase = v_ws + (size_t)bh * DHD * NKVS;

  unsigned char* Pb = &Pl[wid][0];
  const unsigned wsw = (unsigned)(lr * 128) ^ ((unsigned)(lr & 7) << 4);

  f32x4 O[4] = {};
  float m = -1e30f, l = 0.f;

  for (int kt = 0; kt < 32; kt++) {
    const int kv0 = kt * 64;
    f32x4 s[4];
    __builtin_amdgcn_s_setprio(1);
#pragma unroll
    for (int cf = 0; cf < 4; cf++) {
      // K rows as A-operand: row = kv0+cf*16+lr, k = d
      const unsigned short* kp = kbase + (size_t)(kv0 + cf * 16 + lr) * DHD + lg * 8;
      short8 ka0 = *(const short8*)(kp);
      short8 ka1 = *(const short8*)(kp + 32);
      f32x4 zz = {};
      s[cf] = MFMA(ka0, qb0, zz);      // S^T[kv][q]: lane col=q=lr, row=kv
      s[cf] = MFMA(ka1, qb1, s[cf]);
    }
    __builtin_amdgcn_s_setprio(0);
    const unsigned long long mw = mp[kt];
    float pmax = -1e30f;
#pragma unroll
    for (int cf = 0; cf < 4; cf++)
#pragma unroll
      for (int r = 0; r < 4; r++) {
        const bool bit = (mw >> (cf * 16 + lg * 4 + r)) & 1ull;
        const float v = bit ? s[cf][r] : -1e30f;
        s[cf][r] = v;
        pmax = fmaxf(pmax, v);
      }
    pmax = fmaxf(pmax, __shfl_xor(pmax, 16));
    pmax = fmaxf(pmax, __shfl_xor(pmax, 32));
    if (!__all(pmax - m <= 8.f)) {  // defer-max (T13)
      const float mn = fmaxf(m, pmax);
      const float sc = __expf(m - mn);
      m = mn;
      l *= sc;
#pragma unroll
      for (int df = 0; df < 4; df++)
#pragma unroll
        for (int r = 0; r < 4; r++) O[df][r] *= sc;
    }
    float rs = 0.f;
#pragma unroll
    for (int cf = 0; cf < 4; cf++) {
      unsigned pu0, pu1;
      {
        const float p0 = (s[cf][0] > -1e29f) ? __expf(s[cf][0] - m) : 0.f;
        const float p1 = (s[cf][1] > -1e29f) ? __expf(s[cf][1] - m) : 0.f;
        rs += p0 + p1;
        pu0 = (unsigned)f2bf(p0) | ((unsigned)f2bf(p1) << 16);
      }
      {
        const float p0 = (s[cf][2] > -1e29f) ? __expf(s[cf][2] - m) : 0.f;
        const float p1 = (s[cf][3] > -1e29f) ? __expf(s[cf][3] - m) : 0.f;
        rs += p0 + p1;
        pu1 = (unsigned)f2bf(p0) | ((unsigned)f2bf(p1) << 16);
      }
      // P^T[q=lr][kv = cf*16+lg*4 .. +3], swizzled byte addr
      *(uint2*)(Pb + (wsw ^ (unsigned)(cf * 32 + lg * 8))) = make_uint2(pu0, pu1);
    }
    rs += __shfl_xor(rs, 16);
    rs += __shfl_xor(rs, 32);
    l += rs;
    // P^T as B-operand: row q=lr, k = kv = ks*32 + lg*8 + j
    const short8 pb0 = *(const short8*)(Pb + (wsw ^ (unsigned)(lg * 16)));
    const short8 pb1 = *(const short8*)(Pb + (wsw ^ (unsigned)(64 + lg * 16)));
    __builtin_amdgcn_s_setprio(1);
#pragma unroll
    for (int df = 0; df < 4; df++) {
      // V^T rows as A-operand: row d = df*16+lr, k = kv
      const unsigned short* vp = vbase + (size_t)(df * 16 + lr) * NKVS + kv0 + lg * 8;
      short8 va0 = *(const short8*)(vp);
      short8 va1 = *(const short8*)(vp + 32);
      O[df] = MFMA(va0, pb0, O[df]);   // O^T[d][q]: lane col=q=lr, row=d
      O[df] = MFMA(va1, pb1, O[df]);
    }
    __builtin_amdgcn_s_setprio(0);
  }
  const float rinv = (l > 0.f) ? 1.f / l : 0.f;
#pragma unroll
  for (int df = 0; df < 4; df++) {
    us4 o;
#pragma unroll
    for (int r = 0; r < 4; r++) o[r] = f2bf(O[df][r] * rinv);
    *(us4*)(o_ws + ((size_t)b * NQS + q) * DM + h * DHD + df * 16 + lg * 4) = o;
  }
}

// ---------------------------------------------------------------------------
// Kernel 4: output projection: o_ws bf16 [4096][1024] @ Wo^T bf16 + b_o -> fp32
__global__ __launch_bounds__(256) void outproj_kernel(
    const unsigned short* __restrict__ Ain, const unsigned short* __restrict__ Wt,
    const float* __restrict__ bo, float* __restrict__ out) {
  __shared__ unsigned short As[128 * 72];
  __shared__ unsigned short Bs[128 * 72];
  const int m0 = blockIdx.y * 128, j0 = blockIdx.x * 128;
  const int t = threadIdx.x, wid = t >> 6, lane = t & 63, lr = lane & 15, lg = lane >> 4;
  const int wm = wid >> 1, wn = wid & 1;

  f32x4 acc[4][4] = {};
  for (int kt = 0; kt < 16; kt++) {
    const int k0 = kt * 64;
#pragma unroll
    for (int i = 0; i < 4; i++) {
      int idx = t + 256 * i;
      int row = idx >> 3, c8 = (idx & 7) * 8;
      *(short8*)(&As[row * 72 + c8]) =
          *(const short8*)(Ain + (size_t)(m0 + row) * 1024 + k0 + c8);
    }
#pragma unroll
    for (int i = 0; i < 4; i++) {
      int idx = t + 256 * i;
      int j = idx >> 3, c8 = (idx & 7) * 8;
      *(short8*)(&Bs[j * 72 + c8]) =
          *(const short8*)(Wt + (size_t)(j0 + j) * 1024 + k0 + c8);
    }
    __syncthreads();
    short8 a[2][4], b[2][4];
#pragma unroll
    for (int ks = 0; ks < 2; ks++)
#pragma unroll
      for (int mf = 0; mf < 4; mf++)
        a[ks][mf] = *(const short8*)(&As[(wm * 64 + mf * 16 + lr) * 72 + ks * 32 + lg * 8]);
#pragma unroll
    for (int ks = 0; ks < 2; ks++)
#pragma unroll
      for (int nf = 0; nf < 4; nf++)
        b[ks][nf] = *(const short8*)(&Bs[(wn * 64 + nf * 16 + lr) * 72 + ks * 32 + lg * 8]);
#pragma unroll
    for (int ks = 0; ks < 2; ks++)
#pragma unroll
      for (int mf = 0; mf < 4; mf++)
#pragma unroll
        for (int nf = 0; nf < 4; nf++)
          acc[mf][nf] = MFMA(a[ks][mf], b[ks][nf], acc[mf][nf]);
    __syncthreads();
  }
#pragma unroll
  for (int nf = 0; nf < 4; nf++) {
    const int j = j0 + wn * 64 + nf * 16 + lr;
    const float bj = bo[j];
#pragma unroll
    for (int mf = 0; mf < 4; mf++) {
      const int mb = m0 + wm * 64 + mf * 16 + lg * 4;
#pragma unroll
      for (int r = 0; r < 4; r++)
        out[(size_t)(mb + r) * 1024 + j] = acc[mf][nf][r] + bj;
    }
  }
}

// ---------------------------------------------------------------------------
extern "C" void kernel_launch(void* const* d_in, const int* in_sizes, int n_in,
                              void* d_out, int out_size, void* d_ws, size_t ws_size,
                              hipStream_t stream) {
  (void)in_sizes; (void)n_in; (void)out_size; (void)ws_size;
  const float* Q  = (const float*)d_in[0];
  const float* K  = (const float*)d_in[1];
  const float* V  = (const float*)d_in[2];
  const int* mask = (const int*)d_in[3];
  const float* Wq = (const float*)d_in[4];
  const float* bq = (const float*)d_in[5];
  const float* Wk = (const float*)d_in[6];
  const float* bk = (const float*)d_in[7];
  const float* Wv = (const float*)d_in[8];
  const float* bv = (const float*)d_in[9];
  const float* Wo = (const float*)d_in[10];
  const float* bo = (const float*)d_in[11];
  float* out = (float*)d_out;

  char* ws = (char*)d_ws;
  const size_t SZ_BHND = (size_t)BB * NH * NQS * DHD * 2;  // 8388608
  unsigned short* q_ws = (unsigned short*)(ws);
  unsigned short* k_ws = (unsigned short*)(ws + SZ_BHND);
  unsigned short* v_ws = (unsigned short*)(ws + 2 * SZ_BHND);
  unsigned short* o_ws = (unsigned short*)(ws + 3 * SZ_BHND);
  unsigned short* wt   = (unsigned short*)(ws + 4 * SZ_BHND);
  unsigned long long* pk = (unsigned long long*)(ws + 5 * SZ_BHND);

  hipLaunchKernelGGL(wt_kernel, dim3(16, 16, 4), dim3(256), 0, stream, Wq, Wk, Wv, Wo, wt);
  hipLaunchKernelGGL(maskpack_kernel, dim3(4096), dim3(256), 0, stream, mask, pk);
  hipLaunchKernelGGL(proj_kernel, dim3(8, 32, 3), dim3(256), 0, stream,
                     Q, K, V, wt, bq, bk, bv, q_ws, k_ws, v_ws);
  hipLaunchKernelGGL(attn_kernel, dim3(32, 16, 2), dim3(256), 0, stream,
                     q_ws, k_ws, v_ws, pk, o_ws);
  hipLaunchKernelGGL(outproj_kernel, dim3(8, 32), dim3(256), 0, stream,
                     o_ws, wt + (size_t)3 * 1024 * 1024, bo, out);
}

// Round 8
// 399.695 us; speedup vs baseline: 1.2194x; 1.1989x over previous
//
#include <hip/hip_runtime.h>
#include <hip/hip_bf16.h>
#include <stdint.h>

#define DM   1024
#define NH   16
#define DHD  64
#define BB   2
#define NQS  2048
#define NKVS 2048

typedef __attribute__((ext_vector_type(8))) short short8;
typedef __attribute__((ext_vector_type(4))) float f32x4;
typedef __attribute__((ext_vector_type(16))) float f32x16;
typedef __attribute__((ext_vector_type(4))) unsigned short us4;

static __device__ __forceinline__ unsigned short f2bf(float f) {
  union { float f; unsigned u; } v; v.f = f;
  unsigned r = (v.u + 0x7fffu + ((v.u >> 16) & 1u)) >> 16;
  return (unsigned short)r;
}

#define MFMA(a, b, c)   __builtin_amdgcn_mfma_f32_16x16x32_bf16((a), (b), (c), 0, 0, 0)
#define MFMA32(a, b, c) __builtin_amdgcn_mfma_f32_32x32x16_bf16((a), (b), (c), 0, 0, 0)

// ---------------------------------------------------------------------------
// Kernel 0: transpose weights fp32 [K][J] -> bf16 Wt [J][K]
__global__ __launch_bounds__(256) void wt_kernel(
    const float* __restrict__ Wq, const float* __restrict__ Wk,
    const float* __restrict__ Wv, const float* __restrict__ Wo,
    unsigned short* __restrict__ wt) {
  __shared__ unsigned short Ls[64][68];
  const int z = blockIdx.z;
  const float* W = (z == 0) ? Wq : (z == 1) ? Wk : (z == 2) ? Wv : Wo;
  unsigned short* out = wt + (size_t)z * 1024 * 1024;
  const int r0 = blockIdx.y * 64, c0 = blockIdx.x * 64;
  const int t = threadIdx.x;
#pragma unroll
  for (int i = 0; i < 4; i++) {
    int idx = t + 256 * i;
    int row = idx >> 4, c4 = (idx & 15) * 4;
    float4 v = *(const float4*)(W + (size_t)(r0 + row) * 1024 + c0 + c4);
    Ls[row][c4 + 0] = f2bf(v.x);
    Ls[row][c4 + 1] = f2bf(v.y);
    Ls[row][c4 + 2] = f2bf(v.z);
    Ls[row][c4 + 3] = f2bf(v.w);
  }
  __syncthreads();
#pragma unroll
  for (int i = 0; i < 4; i++) {
    int idx = t + 256 * i;
    int jj = idx >> 4, k4 = (idx & 15) * 4;
    us4 o;
    o[0] = Ls[k4 + 0][jj];
    o[1] = Ls[k4 + 1][jj];
    o[2] = Ls[k4 + 2][jj];
    o[3] = Ls[k4 + 3][jj];
    *(us4*)(out + (size_t)(c0 + jj) * 1024 + r0 + k4) = o;
  }
}

// ---------------------------------------------------------------------------
// Kernel 1: pack mask int32 -> bitmask (bit=1 means keep)
__global__ __launch_bounds__(256) void maskpack_kernel(
    const int* __restrict__ mask, unsigned long long* __restrict__ pk) {
  const long long total = (long long)BB * NQS * NKVS;
  const long long stride = (long long)gridDim.x * 256;
  for (long long i = (long long)blockIdx.x * 256 + threadIdx.x; i < total; i += stride) {
    int m = mask[i];
    unsigned long long b = __ballot(m != 0);
    if ((i & 63) == 0) pk[i >> 6] = b;
  }
}

// ---------------------------------------------------------------------------
// Kernel 2: fused QKV projection GEMM.
__global__ __launch_bounds__(256) void proj_kernel(
    const float* __restrict__ Qin, const float* __restrict__ Kin, const float* __restrict__ Vin,
    const unsigned short* __restrict__ wt,
    const float* __restrict__ bq, const float* __restrict__ bk, const float* __restrict__ bv,
    unsigned short* __restrict__ q_ws, unsigned short* __restrict__ k_ws,
    unsigned short* __restrict__ v_ws) {
  __shared__ unsigned short As[128 * 72];
  __shared__ unsigned short Bs[128 * 72];
  const int z = blockIdx.z;
  const float* X = (z == 0) ? Qin : (z == 1) ? Kin : Vin;
  const float* bias = (z == 0) ? bq : (z == 1) ? bk : bv;
  const unsigned short* Wt = wt + (size_t)z * 1024 * 1024;
  const int m0 = blockIdx.y * 128, j0 = blockIdx.x * 128;
  const int t = threadIdx.x, wid = t >> 6, lane = t & 63, lr = lane & 15, lg = lane >> 4;
  const int wm = wid >> 1, wn = wid & 1;

  f32x4 acc[4][4] = {};
  for (int kt = 0; kt < 16; kt++) {
    const int k0 = kt * 64;
#pragma unroll
    for (int i = 0; i < 8; i++) {
      int idx = t + 256 * i;
      int row = idx >> 4, c4 = (idx & 15) * 4;
      float4 v = *(const float4*)(X + (size_t)(m0 + row) * 1024 + k0 + c4);
      us4 o;
      o[0] = f2bf(v.x); o[1] = f2bf(v.y); o[2] = f2bf(v.z); o[3] = f2bf(v.w);
      *(us4*)(&As[row * 72 + c4]) = o;
    }
#pragma unroll
    for (int i = 0; i < 4; i++) {
      int idx = t + 256 * i;
      int j = idx >> 3, c8 = (idx & 7) * 8;
      short8 v = *(const short8*)(Wt + (size_t)(j0 + j) * 1024 + k0 + c8);
      *(short8*)(&Bs[j * 72 + c8]) = v;
    }
    __syncthreads();
    short8 a[2][4], b[2][4];
#pragma unroll
    for (int ks = 0; ks < 2; ks++)
#pragma unroll
      for (int mf = 0; mf < 4; mf++)
        a[ks][mf] = *(const short8*)(&As[(wm * 64 + mf * 16 + lr) * 72 + ks * 32 + lg * 8]);
#pragma unroll
    for (int ks = 0; ks < 2; ks++)
#pragma unroll
      for (int nf = 0; nf < 4; nf++)
        b[ks][nf] = *(const short8*)(&Bs[(wn * 64 + nf * 16 + lr) * 72 + ks * 32 + lg * 8]);
#pragma unroll
    for (int ks = 0; ks < 2; ks++)
#pragma unroll
      for (int mf = 0; mf < 4; mf++)
#pragma unroll
        for (int nf = 0; nf < 4; nf++)
          acc[mf][nf] = MFMA(a[ks][mf], b[ks][nf], acc[mf][nf]);
    __syncthreads();
  }
#pragma unroll
  for (int nf = 0; nf < 4; nf++) {
    const int j = j0 + wn * 64 + nf * 16 + lr;
    const float bj = bias[j];
    const int h = j >> 6, dd = j & 63;
#pragma unroll
    for (int mf = 0; mf < 4; mf++) {
      const int mb = m0 + wm * 64 + mf * 16 + lg * 4;
      const int b_ = mb >> 11, nb = mb & 2047;
      if (z == 2) {
        us4 o;
#pragma unroll
        for (int r = 0; r < 4; r++) o[r] = f2bf(acc[mf][nf][r] + bj);
        *(us4*)(v_ws + ((size_t)(b_ * NH + h) * DHD + dd) * NKVS + nb) = o;
      } else {
        unsigned short* dst = (z == 0) ? q_ws : k_ws;
        const float sc = (z == 0) ? 0.125f : 1.0f;
#pragma unroll
        for (int r = 0; r < 4; r++) {
          float val = (acc[mf][nf][r] + bj) * sc;
          dst[((size_t)(b_ * NH + h) * NQS + nb + r) * DHD + dd] = f2bf(val);
        }
      }
    }
  }
}

// ---------------------------------------------------------------------------
// Kernel 3: flash attention, 32x32 MFMA, fully in-register P via shfl_xor(32).
// 4 waves: wid&1 = q-subtile (32 q each), wid>>1 = kv half (1024 kv each).
// Lane owns q = lane&31 column of S^T; lane pair (lane, lane^32) holds a full
// 32-kv P row. Merge of kv halves via one LDS exchange + barrier at the end.
// grid (NQS/64, NH, BB) = (32,16,2), block 256.
__global__ __launch_bounds__(256) void attn_kernel(
    const unsigned short* __restrict__ q_ws, const unsigned short* __restrict__ k_ws,
    const unsigned short* __restrict__ v_ws, const unsigned long long* __restrict__ pk,
    unsigned short* __restrict__ o_ws) {
  __shared__ float Ml[2][64][2];
  __shared__ float Ol[2][64][36];   // pad 32->36 floats: stride 144B kills bank conflicts
  const int h = blockIdx.y, b = blockIdx.z;
  const int bh = b * NH + h;
  const int t = threadIdx.x, wid = t >> 6, lane = t & 63;
  const int l31 = lane & 31, hi = lane >> 5;
  const int qsub = wid & 1, kvh = wid >> 1;
  const int q = blockIdx.x * 64 + qsub * 32 + l31;

  // Q as B-operand: B[k=d][n=q]: lane holds Q[q=l31][d = ks*16 + hi*8 + j]
  short8 qb[4];
  {
    const unsigned short* qp = q_ws + ((size_t)bh * NQS + q) * DHD + hi * 8;
#pragma unroll
    for (int ks = 0; ks < 4; ks++) qb[ks] = *(const short8*)(qp + ks * 16);
  }
  const unsigned long long* mp = pk + ((size_t)b * NQS + q) * 32;
  const unsigned short* kbase = k_ws + (size_t)bh * NQS * DHD;
  const unsigned short* vbase = v_ws + (size_t)bh * DHD * NKVS;

  f32x16 O[2] = {};
  float m = -1e30f, l = 0.f;

  for (int it = 0; it < 16; it++) {
    const unsigned long long mw = mp[kvh * 16 + it];
#pragma unroll
    for (int st = 0; st < 2; st++) {
      const int kv0 = kvh * 1024 + it * 64 + st * 32;
      const unsigned mword = st ? (unsigned)(mw >> 32) : (unsigned)mw;
      // S^T[kv][q]: A = K rows (row=kv=l31, k=d), B = Q
      f32x16 S = {};
      {
        const unsigned short* kp = kbase + (size_t)(kv0 + l31) * DHD + hi * 8;
#pragma unroll
        for (int ks = 0; ks < 4; ks++)
          S = MFMA32(*(const short8*)(kp + ks * 16), qb[ks], S);
      }
      float p[16];
      float pmax = -1e30f;
#pragma unroll
      for (int r = 0; r < 16; r++) {
        const int kvr = (r & 3) + 8 * (r >> 2) + 4 * hi;
        const bool bit = (mword >> kvr) & 1u;
        const float sv = bit ? S[r] : -1e30f;
        p[r] = sv;
        pmax = fmaxf(pmax, sv);
      }
      pmax = fmaxf(pmax, __shfl_xor(pmax, 32));
      if (!__all(pmax - m <= 8.f)) {  // defer-max (T13)
        const float mn = fmaxf(m, pmax);
        const float sc = __expf(m - mn);
        m = mn; l *= sc;
#pragma unroll
        for (int dt = 0; dt < 2; dt++)
#pragma unroll
          for (int r = 0; r < 16; r++) O[dt][r] *= sc;
      }
      float rs = 0.f;
#pragma unroll
      for (int r = 0; r < 16; r++) {
        p[r] = (p[r] > -1e29f) ? __expf(p[r] - m) : 0.f;
        rs += p[r];
      }
      rs += __shfl_xor(rs, 32);
      l += rs;
      // pack P to bf16 pairs; exchange halves with lane^32; build PV B-frags
      unsigned pk8[8], sw[8];
#pragma unroll
      for (int i = 0; i < 8; i++)
        pk8[i] = (unsigned)f2bf(p[2 * i]) | ((unsigned)f2bf(p[2 * i + 1]) << 16);
#pragma unroll
      for (int i = 0; i < 8; i++) sw[i] = __shfl_xor(pk8[i], 32);
      union { unsigned u[4]; short8 s; } pb0, pb1;
      pb0.u[0] = hi ? sw[2] : pk8[0];
      pb0.u[1] = hi ? sw[3] : pk8[1];
      pb0.u[2] = hi ? pk8[2] : sw[0];
      pb0.u[3] = hi ? pk8[3] : sw[1];
      pb1.u[0] = hi ? sw[6] : pk8[4];
      pb1.u[1] = hi ? sw[7] : pk8[5];
      pb1.u[2] = hi ? pk8[6] : sw[4];
      pb1.u[3] = hi ? pk8[7] : sw[5];
      // O^T[d][q] += V^T . P^T  (A = V^T rows: row=d, k=kv)
#pragma unroll
      for (int dt = 0; dt < 2; dt++) {
        const unsigned short* vp = vbase + (size_t)(dt * 32 + l31) * NKVS + kv0 + hi * 8;
        short8 va0 = *(const short8*)(vp);
        short8 va1 = *(const short8*)(vp + 16);
        O[dt] = MFMA32(va0, pb0.s, O[dt]);
        O[dt] = MFMA32(va1, pb1.s, O[dt]);
      }
    }
  }
  // merge kv halves
  if (kvh == 1) {
    Ml[qsub][lane][0] = m;
    Ml[qsub][lane][1] = l;
#pragma unroll
    for (int dt = 0; dt < 2; dt++)
#pragma unroll
      for (int g = 0; g < 4; g++) {
        f32x4 v;
#pragma unroll
        for (int j = 0; j < 4; j++) v[j] = O[dt][g * 4 + j];
        *(f32x4*)&Ol[qsub][lane][dt * 16 + g * 4] = v;
      }
  }
  __syncthreads();
  if (kvh == 0) {
    const float m1 = Ml[qsub][lane][0], l1 = Ml[qsub][lane][1];
    const float M = fmaxf(m, m1);
    const float a0 = __expf(m - M), a1 = __expf(m1 - M);
    const float L = l * a0 + l1 * a1;
    const float rinv = (L > 0.f) ? 1.f / L : 0.f;
    const float s0 = a0 * rinv, s1 = a1 * rinv;
#pragma unroll
    for (int dt = 0; dt < 2; dt++)
#pragma unroll
      for (int g = 0; g < 4; g++) {
        us4 o;
#pragma unroll
        for (int j = 0; j < 4; j++) {
          const float v = O[dt][g * 4 + j] * s0 + Ol[qsub][lane][dt * 16 + g * 4 + j] * s1;
          o[j] = f2bf(v);
        }
        const int d = dt * 32 + g * 8 + hi * 4;
        *(us4*)(o_ws + ((size_t)b * NQS + q) * DM + h * DHD + d) = o;
      }
  }
}

// ---------------------------------------------------------------------------
// Kernel 4: output projection: o_ws bf16 [4096][1024] @ Wo^T bf16 + b_o -> fp32
__global__ __launch_bounds__(256) void outproj_kernel(
    const unsigned short* __restrict__ Ain, const unsigned short* __restrict__ Wt,
    const float* __restrict__ bo, float* __restrict__ out) {
  __shared__ unsigned short As[128 * 72];
  __shared__ unsigned short Bs[128 * 72];
  const int m0 = blockIdx.y * 128, j0 = blockIdx.x * 128;
  const int t = threadIdx.x, wid = t >> 6, lane = t & 63, lr = lane & 15, lg = lane >> 4;
  const int wm = wid >> 1, wn = wid & 1;

  f32x4 acc[4][4] = {};
  for (int kt = 0; kt < 16; kt++) {
    const int k0 = kt * 64;
#pragma unroll
    for (int i = 0; i < 4; i++) {
      int idx = t + 256 * i;
      int row = idx >> 3, c8 = (idx & 7) * 8;
      *(short8*)(&As[row * 72 + c8]) =
          *(const short8*)(Ain + (size_t)(m0 + row) * 1024 + k0 + c8);
    }
#pragma unroll
    for (int i = 0; i < 4; i++) {
      int idx = t + 256 * i;
      int j = idx >> 3, c8 = (idx & 7) * 8;
      *(short8*)(&Bs[j * 72 + c8]) =
          *(const short8*)(Wt + (size_t)(j0 + j) * 1024 + k0 + c8);
    }
    __syncthreads();
    short8 a[2][4], b[2][4];
#pragma unroll
    for (int ks = 0; ks < 2; ks++)
#pragma unroll
      for (int mf = 0; mf < 4; mf++)
        a[ks][mf] = *(const short8*)(&As[(wm * 64 + mf * 16 + lr) * 72 + ks * 32 + lg * 8]);
#pragma unroll
    for (int ks = 0; ks < 2; ks++)
#pragma unroll
      for (int nf = 0; nf < 4; nf++)
        b[ks][nf] = *(const short8*)(&Bs[(wn * 64 + nf * 16 + lr) * 72 + ks * 32 + lg * 8]);
#pragma unroll
    for (int ks = 0; ks < 2; ks++)
#pragma unroll
      for (int mf = 0; mf < 4; mf++)
#pragma unroll
        for (int nf = 0; nf < 4; nf++)
          acc[mf][nf] = MFMA(a[ks][mf], b[ks][nf], acc[mf][nf]);
    __syncthreads();
  }
#pragma unroll
  for (int nf = 0; nf < 4; nf++) {
    const int j = j0 + wn * 64 + nf * 16 + lr;
    const float bj = bo[j];
#pragma unroll
    for (int mf = 0; mf < 4; mf++) {
      const int mb = m0 + wm * 64 + mf * 16 + lg * 4;
#pragma unroll
      for (int r = 0; r < 4; r++)
        out[(size_t)(mb + r) * 1024 + j] = acc[mf][nf][r] + bj;
    }
  }
}

// ---------------------------------------------------------------------------
extern "C" void kernel_launch(void* const* d_in, const int* in_sizes, int n_in,
                              void* d_out, int out_size, void* d_ws, size_t ws_size,
                              hipStream_t stream) {
  (void)in_sizes; (void)n_in; (void)out_size; (void)ws_size;
  const float* Q  = (const float*)d_in[0];
  const float* K  = (const float*)d_in[1];
  const float* V  = (const float*)d_in[2];
  const int* mask = (const int*)d_in[3];
  const float* Wq = (const float*)d_in[4];
  const float* bq = (const float*)d_in[5];
  const float* Wk = (const float*)d_in[6];
  const float* bk = (const float*)d_in[7];
  const float* Wv = (const float*)d_in[8];
  const float* bv = (const float*)d_in[9];
  const float* Wo = (const float*)d_in[10];
  const float* bo = (const float*)d_in[11];
  float* out = (float*)d_out;

  char* ws = (char*)d_ws;
  const size_t SZ_BHND = (size_t)BB * NH * NQS * DHD * 2;  // 8388608
  unsigned short* q_ws = (unsigned short*)(ws);
  unsigned short* k_ws = (unsigned short*)(ws + SZ_BHND);
  unsigned short* v_ws = (unsigned short*)(ws + 2 * SZ_BHND);
  unsigned short* o_ws = (unsigned short*)(ws + 3 * SZ_BHND);
  unsigned short* wt   = (unsigned short*)(ws + 4 * SZ_BHND);
  unsigned long long* pk = (unsigned long long*)(ws + 5 * SZ_BHND);

  hipLaunchKernelGGL(wt_kernel, dim3(16, 16, 4), dim3(256), 0, stream, Wq, Wk, Wv, Wo, wt);
  hipLaunchKernelGGL(maskpack_kernel, dim3(4096), dim3(256), 0, stream, mask, pk);
  hipLaunchKernelGGL(proj_kernel, dim3(8, 32, 3), dim3(256), 0, stream,
                     Q, K, V, wt, bq, bk, bv, q_ws, k_ws, v_ws);
  hipLaunchKernelGGL(attn_kernel, dim3(32, 16, 2), dim3(256), 0, stream,
                     q_ws, k_ws, v_ws, pk, o_ws);
  hipLaunchKernelGGL(outproj_kernel, dim3(8, 32), dim3(256), 0, stream,
                     o_ws, wt + (size_t)3 * 1024 * 1024, bo, out);
}

// Round 11
// 385.585 us; speedup vs baseline: 1.2640x; 1.0366x over previous
//
#include <hip/hip_runtime.h>
#include <hip/hip_bf16.h>
#include <stdint.h>

#define DM   1024
#define NH   16
#define DHD  64
#define BB   2
#define NQS  2048
#define NKVS 2048

typedef __attribute__((ext_vector_type(8))) short short8;
typedef __attribute__((ext_vector_type(4))) float f32x4;
typedef __attribute__((ext_vector_type(16))) float f32x16;
typedef __attribute__((ext_vector_type(4))) unsigned short us4;

static __device__ __forceinline__ unsigned short f2bf(float f) {
  union { float f; unsigned u; } v; v.f = f;
  unsigned r = (v.u + 0x7fffu + ((v.u >> 16) & 1u)) >> 16;
  return (unsigned short)r;
}

#define MFMA(a, b, c)   __builtin_amdgcn_mfma_f32_16x16x32_bf16((a), (b), (c), 0, 0, 0)
#define MFMA32(a, b, c) __builtin_amdgcn_mfma_f32_32x32x16_bf16((a), (b), (c), 0, 0, 0)

// ---------------------------------------------------------------------------
// Kernel 0: transpose weights fp32 [K][J] -> bf16 Wt [J][K]
__global__ __launch_bounds__(256) void wt_kernel(
    const float* __restrict__ Wq, const float* __restrict__ Wk,
    const float* __restrict__ Wv, const float* __restrict__ Wo,
    unsigned short* __restrict__ wt) {
  __shared__ unsigned short Ls[64][68];
  const int z = blockIdx.z;
  const float* W = (z == 0) ? Wq : (z == 1) ? Wk : (z == 2) ? Wv : Wo;
  unsigned short* out = wt + (size_t)z * 1024 * 1024;
  const int r0 = blockIdx.y * 64, c0 = blockIdx.x * 64;
  const int t = threadIdx.x;
#pragma unroll
  for (int i = 0; i < 4; i++) {
    int idx = t + 256 * i;
    int row = idx >> 4, c4 = (idx & 15) * 4;
    float4 v = *(const float4*)(W + (size_t)(r0 + row) * 1024 + c0 + c4);
    Ls[row][c4 + 0] = f2bf(v.x);
    Ls[row][c4 + 1] = f2bf(v.y);
    Ls[row][c4 + 2] = f2bf(v.z);
    Ls[row][c4 + 3] = f2bf(v.w);
  }
  __syncthreads();
#pragma unroll
  for (int i = 0; i < 4; i++) {
    int idx = t + 256 * i;
    int jj = idx >> 4, k4 = (idx & 15) * 4;
    us4 o;
    o[0] = Ls[k4 + 0][jj];
    o[1] = Ls[k4 + 1][jj];
    o[2] = Ls[k4 + 2][jj];
    o[3] = Ls[k4 + 3][jj];
    *(us4*)(out + (size_t)(c0 + jj) * 1024 + r0 + k4) = o;
  }
}

// ---------------------------------------------------------------------------
// Kernel 1: pack mask int32 -> bitmask (bit=1 means keep)
__global__ __launch_bounds__(256) void maskpack_kernel(
    const int* __restrict__ mask, unsigned long long* __restrict__ pk) {
  const long long total = (long long)BB * NQS * NKVS;
  const long long stride = (long long)gridDim.x * 256;
  for (long long i = (long long)blockIdx.x * 256 + threadIdx.x; i < total; i += stride) {
    int m = mask[i];
    unsigned long long b = __ballot(m != 0);
    if ((i & 63) == 0) pk[i >> 6] = b;
  }
}

// ---------------------------------------------------------------------------
// Kernel 2: fused QKV projection GEMM.
__global__ __launch_bounds__(256) void proj_kernel(
    const float* __restrict__ Qin, const float* __restrict__ Kin, const float* __restrict__ Vin,
    const unsigned short* __restrict__ wt,
    const float* __restrict__ bq, const float* __restrict__ bk, const float* __restrict__ bv,
    unsigned short* __restrict__ q_ws, unsigned short* __restrict__ k_ws,
    unsigned short* __restrict__ v_ws) {
  __shared__ unsigned short As[128 * 72];
  __shared__ unsigned short Bs[128 * 72];
  const int z = blockIdx.z;
  const float* X = (z == 0) ? Qin : (z == 1) ? Kin : Vin;
  const float* bias = (z == 0) ? bq : (z == 1) ? bk : bv;
  const unsigned short* Wt = wt + (size_t)z * 1024 * 1024;
  const int m0 = blockIdx.y * 128, j0 = blockIdx.x * 128;
  const int t = threadIdx.x, wid = t >> 6, lane = t & 63, lr = lane & 15, lg = lane >> 4;
  const int wm = wid >> 1, wn = wid & 1;

  f32x4 acc[4][4] = {};
  for (int kt = 0; kt < 16; kt++) {
    const int k0 = kt * 64;
#pragma unroll
    for (int i = 0; i < 8; i++) {
      int idx = t + 256 * i;
      int row = idx >> 4, c4 = (idx & 15) * 4;
      float4 v = *(const float4*)(X + (size_t)(m0 + row) * 1024 + k0 + c4);
      us4 o;
      o[0] = f2bf(v.x); o[1] = f2bf(v.y); o[2] = f2bf(v.z); o[3] = f2bf(v.w);
      *(us4*)(&As[row * 72 + c4]) = o;
    }
#pragma unroll
    for (int i = 0; i < 4; i++) {
      int idx = t + 256 * i;
      int j = idx >> 3, c8 = (idx & 7) * 8;
      short8 v = *(const short8*)(Wt + (size_t)(j0 + j) * 1024 + k0 + c8);
      *(short8*)(&Bs[j * 72 + c8]) = v;
    }
    __syncthreads();
    short8 a[2][4], b[2][4];
#pragma unroll
    for (int ks = 0; ks < 2; ks++)
#pragma unroll
      for (int mf = 0; mf < 4; mf++)
        a[ks][mf] = *(const short8*)(&As[(wm * 64 + mf * 16 + lr) * 72 + ks * 32 + lg * 8]);
#pragma unroll
    for (int ks = 0; ks < 2; ks++)
#pragma unroll
      for (int nf = 0; nf < 4; nf++)
        b[ks][nf] = *(const short8*)(&Bs[(wn * 64 + nf * 16 + lr) * 72 + ks * 32 + lg * 8]);
#pragma unroll
    for (int ks = 0; ks < 2; ks++)
#pragma unroll
      for (int mf = 0; mf < 4; mf++)
#pragma unroll
        for (int nf = 0; nf < 4; nf++)
          acc[mf][nf] = MFMA(a[ks][mf], b[ks][nf], acc[mf][nf]);
    __syncthreads();
  }
#pragma unroll
  for (int nf = 0; nf < 4; nf++) {
    const int j = j0 + wn * 64 + nf * 16 + lr;
    const float bj = bias[j];
    const int h = j >> 6, dd = j & 63;
#pragma unroll
    for (int mf = 0; mf < 4; mf++) {
      const int mb = m0 + wm * 64 + mf * 16 + lg * 4;
      const int b_ = mb >> 11, nb = mb & 2047;
      if (z == 2) {
        us4 o;
#pragma unroll
        for (int r = 0; r < 4; r++) o[r] = f2bf(acc[mf][nf][r] + bj);
        *(us4*)(v_ws + ((size_t)(b_ * NH + h) * DHD + dd) * NKVS + nb) = o;
      } else {
        unsigned short* dst = (z == 0) ? q_ws : k_ws;
        const float sc = (z == 0) ? 0.125f : 1.0f;
#pragma unroll
        for (int r = 0; r < 4; r++) {
          float val = (acc[mf][nf][r] + bj) * sc;
          dst[((size_t)(b_ * NH + h) * NQS + nb + r) * DHD + dd] = f2bf(val);
        }
      }
    }
  }
}

// ---------------------------------------------------------------------------
// Kernel 3: flash attention, 32x32 MFMA, in-register P via shfl_xor(32).
// 32 q per block; 4 waves each own a 512-kv quarter (16 subtiles of 32 kv).
// 4-way merge at the end: waves 1-3 spill (m,l,O) to padded LDS, wave 0
// combines + writes. grid (NQS/32, NH, BB) = (64,16,2), block 256.
__global__ __launch_bounds__(256) void attn_kernel(
    const unsigned short* __restrict__ q_ws, const unsigned short* __restrict__ k_ws,
    const unsigned short* __restrict__ v_ws, const unsigned* __restrict__ pk32,
    unsigned short* __restrict__ o_ws) {
  __shared__ float Ol[3][64][34];   // stride 34 floats: lane*34 mod 32 -> 2-way (free)
  __shared__ float Ml[3][64][2];
  const int h = blockIdx.y, b = blockIdx.z;
  const int bh = b * NH + h;
  const int t = threadIdx.x, w = t >> 6, lane = t & 63;
  const int l31 = lane & 31, hi = lane >> 5;
  const int q = blockIdx.x * 32 + l31;

  // Q as B-operand: lane holds Q[q=l31][d = ks*16 + hi*8 + j]
  short8 qb[4];
  {
    const unsigned short* qp = q_ws + ((size_t)bh * NQS + q) * DHD + hi * 8;
#pragma unroll
    for (int ks = 0; ks < 4; ks++) qb[ks] = *(const short8*)(qp + ks * 16);
  }
  // mask as u32 words: word index = (b*NQS+q)*64 + kv/32
  const unsigned* mp = pk32 + ((size_t)b * NQS + q) * 64 + w * 16;
  const unsigned short* kbase = k_ws + ((size_t)bh * NQS + w * 512) * DHD;
  const unsigned short* vbase = v_ws + (size_t)bh * DHD * NKVS;

  f32x16 O[2] = {};
  float m = -1e30f, l = 0.f;

  for (int it = 0; it < 16; it++) {
    const int kv0 = w * 512 + it * 32;
    const unsigned mword = mp[it];
    // S^T[kv][q]: A = K rows (row=kv, k=d), B = Q
    f32x16 S = {};
    {
      const unsigned short* kp = kbase + (size_t)(it * 32 + l31) * DHD + hi * 8;
#pragma unroll
      for (int ks = 0; ks < 4; ks++)
        S = MFMA32(*(const short8*)(kp + ks * 16), qb[ks], S);
    }
    float p[16];
    float pmax = -1e30f;
#pragma unroll
    for (int r = 0; r < 16; r++) {
      const int kvr = (r & 3) + 8 * (r >> 2) + 4 * hi;
      const bool bit = (mword >> kvr) & 1u;
      const float sv = bit ? S[r] : -1e30f;
      p[r] = sv;
      pmax = fmaxf(pmax, sv);
    }
    pmax = fmaxf(pmax, __shfl_xor(pmax, 32));
    if (!__all(pmax - m <= 8.f)) {  // defer-max (T13)
      const float mn = fmaxf(m, pmax);
      const float sc = __expf(m - mn);
      m = mn; l *= sc;
#pragma unroll
      for (int dt = 0; dt < 2; dt++)
#pragma unroll
        for (int r = 0; r < 16; r++) O[dt][r] *= sc;
    }
    float rs = 0.f;
#pragma unroll
    for (int r = 0; r < 16; r++) {
      p[r] = (p[r] > -1e29f) ? __expf(p[r] - m) : 0.f;
      rs += p[r];
    }
    rs += __shfl_xor(rs, 32);
    l += rs;
    // pack P to bf16 pairs; exchange halves with lane^32; build PV B-frags
    unsigned pk8[8], sw[8];
#pragma unroll
    for (int i = 0; i < 8; i++)
      pk8[i] = (unsigned)f2bf(p[2 * i]) | ((unsigned)f2bf(p[2 * i + 1]) << 16);
#pragma unroll
    for (int i = 0; i < 8; i++) sw[i] = __shfl_xor(pk8[i], 32);
    union { unsigned u[4]; short8 s; } pb0, pb1;
    pb0.u[0] = hi ? sw[2] : pk8[0];
    pb0.u[1] = hi ? sw[3] : pk8[1];
    pb0.u[2] = hi ? pk8[2] : sw[0];
    pb0.u[3] = hi ? pk8[3] : sw[1];
    pb1.u[0] = hi ? sw[6] : pk8[4];
    pb1.u[1] = hi ? sw[7] : pk8[5];
    pb1.u[2] = hi ? pk8[6] : sw[4];
    pb1.u[3] = hi ? pk8[7] : sw[5];
    // O^T[d][q] += V^T . P^T  (A = V^T rows: row=d, k=kv)
#pragma unroll
    for (int dt = 0; dt < 2; dt++) {
      const unsigned short* vp = vbase + (size_t)(dt * 32 + l31) * NKVS + kv0 + hi * 8;
      short8 va0 = *(const short8*)(vp);
      short8 va1 = *(const short8*)(vp + 16);
      O[dt] = MFMA32(va0, pb0.s, O[dt]);
      O[dt] = MFMA32(va1, pb1.s, O[dt]);
    }
  }
  // 4-way merge: waves 1-3 spill, wave 0 combines
  if (w) {
    Ml[w - 1][lane][0] = m;
    Ml[w - 1][lane][1] = l;
#pragma unroll
    for (int dt = 0; dt < 2; dt++)
#pragma unroll
      for (int g = 0; g < 4; g++) {
        f32x4 v;
#pragma unroll
        for (int j = 0; j < 4; j++) v[j] = O[dt][g * 4 + j];
        *(f32x4*)&Ol[w - 1][lane][dt * 16 + g * 4] = v;
      }
  }
  __syncthreads();
  if (w == 0) {
    float mo[3], lo[3];
    float M = m;
#pragma unroll
    for (int j = 0; j < 3; j++) {
      mo[j] = Ml[j][lane][0];
      lo[j] = Ml[j][lane][1];
      M = fmaxf(M, mo[j]);
    }
    const float a0 = __expf(m - M);
    float aj[3];
    float L = l * a0;
#pragma unroll
    for (int j = 0; j < 3; j++) {
      aj[j] = __expf(mo[j] - M);
      L += lo[j] * aj[j];
    }
    const float rinv = (L > 0.f) ? 1.f / L : 0.f;
    const float s0 = a0 * rinv;
#pragma unroll
    for (int dt = 0; dt < 2; dt++)
#pragma unroll
      for (int g = 0; g < 4; g++) {
        f32x4 acc;
#pragma unroll
        for (int j = 0; j < 4; j++) acc[j] = O[dt][g * 4 + j] * s0;
#pragma unroll
        for (int j = 0; j < 3; j++) {
          const f32x4 ov = *(const f32x4*)&Ol[j][lane][dt * 16 + g * 4];
          const float sj = aj[j] * rinv;
#pragma unroll
          for (int jj = 0; jj < 4; jj++) acc[jj] += ov[jj] * sj;
        }
        us4 o;
#pragma unroll
        for (int jj = 0; jj < 4; jj++) o[jj] = f2bf(acc[jj]);
        const int d = dt * 32 + g * 8 + hi * 4;
        *(us4*)(o_ws + ((size_t)b * NQS + q) * DM + h * DHD + d) = o;
      }
  }
}

// ---------------------------------------------------------------------------
// Kernel 4: output projection: o_ws bf16 [4096][1024] @ Wo^T bf16 + b_o -> fp32
__global__ __launch_bounds__(256) void outproj_kernel(
    const unsigned short* __restrict__ Ain, const unsigned short* __restrict__ Wt,
    const float* __restrict__ bo, float* __restrict__ out) {
  __shared__ unsigned short As[128 * 72];
  __shared__ unsigned short Bs[128 * 72];
  const int m0 = blockIdx.y * 128, j0 = blockIdx.x * 128;
  const int t = threadIdx.x, wid = t >> 6, lane = t & 63, lr = lane & 15, lg = lane >> 4;
  const int wm = wid >> 1, wn = wid & 1;

  f32x4 acc[4][4] = {};
  for (int kt = 0; kt < 16; kt++) {
    const int k0 = kt * 64;
#pragma unroll
    for (int i = 0; i < 4; i++) {
      int idx = t + 256 * i;
      int row = idx >> 3, c8 = (idx & 7) * 8;
      *(short8*)(&As[row * 72 + c8]) =
          *(const short8*)(Ain + (size_t)(m0 + row) * 1024 + k0 + c8);
    }
#pragma unroll
    for (int i = 0; i < 4; i++) {
      int idx = t + 256 * i;
      int j = idx >> 3, c8 = (idx & 7) * 8;
      *(short8*)(&Bs[j * 72 + c8]) =
          *(const short8*)(Wt + (size_t)(j0 + j) * 1024 + k0 + c8);
    }
    __syncthreads();
    short8 a[2][4], b[2][4];
#pragma unroll
    for (int ks = 0; ks < 2; ks++)
#pragma unroll
      for (int mf = 0; mf < 4; mf++)
        a[ks][mf] = *(const short8*)(&As[(wm * 64 + mf * 16 + lr) * 72 + ks * 32 + lg * 8]);
#pragma unroll
    for (int ks = 0; ks < 2; ks++)
#pragma unroll
      for (int nf = 0; nf < 4; nf++)
        b[ks][nf] = *(const short8*)(&Bs[(wn * 64 + nf * 16 + lr) * 72 + ks * 32 + lg * 8]);
#pragma unroll
    for (int ks = 0; ks < 2; ks++)
#pragma unroll
      for (int mf = 0; mf < 4; mf++)
#pragma unroll
        for (int nf = 0; nf < 4; nf++)
          acc[mf][nf] = MFMA(a[ks][mf], b[ks][nf], acc[mf][nf]);
    __syncthreads();
  }
#pragma unroll
  for (int nf = 0; nf < 4; nf++) {
    const int j = j0 + wn * 64 + nf * 16 + lr;
    const float bj = bo[j];
#pragma unroll
    for (int mf = 0; mf < 4; mf++) {
      const int mb = m0 + wm * 64 + mf * 16 + lg * 4;
#pragma unroll
      for (int r = 0; r < 4; r++)
        out[(size_t)(mb + r) * 1024 + j] = acc[mf][nf][r] + bj;
    }
  }
}

// ---------------------------------------------------------------------------
extern "C" void kernel_launch(void* const* d_in, const int* in_sizes, int n_in,
                              void* d_out, int out_size, void* d_ws, size_t ws_size,
                              hipStream_t stream) {
  (void)in_sizes; (void)n_in; (void)out_size; (void)ws_size;
  const float* Q  = (const float*)d_in[0];
  const float* K  = (const float*)d_in[1];
  const float* V  = (const float*)d_in[2];
  const int* mask = (const int*)d_in[3];
  const float* Wq = (const float*)d_in[4];
  const float* bq = (const float*)d_in[5];
  const float* Wk = (const float*)d_in[6];
  const float* bk = (const float*)d_in[7];
  const float* Wv = (const float*)d_in[8];
  const float* bv = (const float*)d_in[9];
  const float* Wo = (const float*)d_in[10];
  const float* bo = (const float*)d_in[11];
  float* out = (float*)d_out;

  char* ws = (char*)d_ws;
  const size_t SZ_BHND = (size_t)BB * NH * NQS * DHD * 2;  // 8388608
  unsigned short* q_ws = (unsigned short*)(ws);
  unsigned short* k_ws = (unsigned short*)(ws + SZ_BHND);
  unsigned short* v_ws = (unsigned short*)(ws + 2 * SZ_BHND);
  unsigned short* o_ws = (unsigned short*)(ws + 3 * SZ_BHND);
  unsigned short* wt   = (unsigned short*)(ws + 4 * SZ_BHND);
  unsigned long long* pk = (unsigned long long*)(ws + 5 * SZ_BHND);

  hipLaunchKernelGGL(wt_kernel, dim3(16, 16, 4), dim3(256), 0, stream, Wq, Wk, Wv, Wo, wt);
  hipLaunchKernelGGL(maskpack_kernel, dim3(4096), dim3(256), 0, stream, mask, pk);
  hipLaunchKernelGGL(proj_kernel, dim3(8, 32, 3), dim3(256), 0, stream,
                     Q, K, V, wt, bq, bk, bv, q_ws, k_ws, v_ws);
  hipLaunchKernelGGL(attn_kernel, dim3(64, 16, 2), dim3(256), 0, stream,
                     q_ws, k_ws, v_ws, (const unsigned*)pk, o_ws);
  hipLaunchKernelGGL(outproj_kernel, dim3(8, 32), dim3(256), 0, stream,
                     o_ws, wt + (size_t)3 * 1024 * 1024, bo, out);
}